// Round 9
// baseline (309.935 us; speedup 1.0000x reference)
//
#include <hip/hip_runtime.h>

// Problem constants
#define BB 2
#define CC 64
#define KK 27
#define S_TOT 32768  // 32^3
#define BN_EPS 1e-5f

// ws layout: xT[2][32768][64] floats (16.8 MB) then ker[2][216][32768] (56.6 MB)
#define XT_FLOATS ((size_t)BB * S_TOT * CC)

// ---------------------------------------------------------------------------
// K1: transpose x[b][c][s] -> xT[b][s][c]  (LDS-tiled, verified since R5).
// ---------------------------------------------------------------------------
__global__ __launch_bounds__(256) void xpose_kernel(const float* __restrict__ x,
                                                    float* __restrict__ xT) {
  __shared__ float t[64 * 65];
  const int tid = threadIdx.x;
  const int blk = blockIdx.x;
  const int b   = blk >> 9;
  const int s0  = (blk & 511) << 6;
  const float* xb = x + ((size_t)b << 21);
  {
    const int cq = tid >> 4;
    const int sq = (tid & 15) << 2;
#pragma unroll
    for (int i = 0; i < 4; ++i) {
      int c = cq + (i << 4);
      float4 v = *(const float4*)(xb + ((size_t)c << 15) + s0 + sq);
      t[c * 65 + sq + 0] = v.x;
      t[c * 65 + sq + 1] = v.y;
      t[c * 65 + sq + 2] = v.z;
      t[c * 65 + sq + 3] = v.w;
    }
  }
  __syncthreads();
  {
    float* xTb = xT + ((size_t)b << 21);
    const int si = tid >> 2;
    const int cb = (tid & 3) << 4;
#pragma unroll
    for (int j = 0; j < 4; ++j) {
      int c = cb + (j << 2);
      float4 w;
      w.x = t[(c + 0) * 65 + si];
      w.y = t[(c + 1) * 65 + si];
      w.z = t[(c + 2) * 65 + si];
      w.w = t[(c + 3) * 65 + si];
      *(float4*)(xTb + ((size_t)(s0 + si) << 6) + c) = w;
    }
  }
}

// ---------------------------------------------------------------------------
// K2: kernel generation. Block (b, p, tile), 4 waves; wave w owns group
// g=4p+w. GEMM2's j-dimension tiled in 3 chunks of 9: acc[9] live + 9-store
// tail per chunk keeps peak pressure ~40 VGPR (R8's 27-way store tail made
// ~81 regs live under the 64 cap -> allocator spilled ALL arrays, 680 MB of
// scratch traffic). Chunking re-reads sv 3x from LDS — ~6 us, cheap.
// ---------------------------------------------------------------------------
__global__ __launch_bounds__(256, 8) void kergen_kernel(
    const float* __restrict__ x, const float* __restrict__ wr,
    const float* __restrict__ wsp, const float* __restrict__ gamma,
    const float* __restrict__ beta, const float* __restrict__ mean,
    const float* __restrict__ var, float* __restrict__ ker) {
  __shared__ float sv[CC * 64];  // 16 KB

  const int tid = threadIdx.x;
  const int blk = blockIdx.x;
  const int b   = blk >> 10;
  const int p   = (blk >> 9) & 1;
  const int s0  = (blk & 511) << 6;
  const int si  = tid & 63;
  const int w   = __builtin_amdgcn_readfirstlane(tid >> 6);
  const int g   = (p << 2) + w;

  const float* xs0 = x + ((size_t)b << 21) + s0 + si;

  // GEMM1 + BN + ReLU -> sv (wave w computes channels 16w..16w+15)
  {
    float acc[16];
#pragma unroll
    for (int j = 0; j < 16; ++j) acc[j] = 0.f;
#pragma unroll
    for (int half = 0; half < 2; ++half) {
      float xv[32];
#pragma unroll
      for (int c = 0; c < 32; ++c)
        xv[c] = xs0[(size_t)(half * 32 + c) << 15];
      const float* wrw = wr + (w * 16) * CC + half * 32;
#pragma unroll
      for (int j = 0; j < 16; ++j) {
        const float* r0 = wrw + j * CC;
        float a0 = 0.f, a1 = 0.f;
#pragma unroll
        for (int c = 0; c < 32; c += 2) {
          a0 = fmaf(r0[c],     xv[c],     a0);
          a1 = fmaf(r0[c + 1], xv[c + 1], a1);
        }
        acc[j] += a0 + a1;
      }
    }
#pragma unroll
    for (int j = 0; j < 16; ++j) {
      int o = w * 16 + j;
      float v = (acc[j] - mean[o]) * rsqrtf(var[o] + BN_EPS) * gamma[o] + beta[o];
      sv[o * 64 + si] = v > 0.f ? v : 0.f;
    }
  }
  __syncthreads();

  // GEMM2 -> ker, j tiled by 9
  float* kb = ker + (((size_t)(b * 216 + g * KK)) << 15) + s0 + si;
#pragma unroll
  for (int jt = 0; jt < 3; ++jt) {
    float acc[9];
#pragma unroll
    for (int j = 0; j < 9; ++j) acc[j] = 0.f;
#pragma unroll
    for (int e = 0; e < 8; ++e) {
      float xv[8];
#pragma unroll
      for (int c = 0; c < 8; ++c) xv[c] = sv[(e * 8 + c) * 64 + si];
      const float* wsw = wsp + (g * KK + jt * 9) * CC + e * 8;
#pragma unroll
      for (int j = 0; j < 9; ++j) {
        const float* r = wsw + j * CC;
        float a0 = 0.f, a1 = 0.f;
#pragma unroll
        for (int c = 0; c < 8; c += 2) {
          a0 = fmaf(r[c],     xv[c],     a0);
          a1 = fmaf(r[c + 1], xv[c + 1], a1);
        }
        acc[j] += a0 + a1;
      }
    }
#pragma unroll
    for (int j = 0; j < 9; ++j)
      kb[(size_t)(jt * 9 + j) << 15] = acc[j];
  }
}

// ---------------------------------------------------------------------------
// K3: gather-reduce (unchanged from R8 — not the bottleneck). Rolled k-loop,
// no kreg array; ker + xT are L3-resident.
// ---------------------------------------------------------------------------
__global__ __launch_bounds__(256, 8) void gather_kernel(
    const float* __restrict__ xT, const float* __restrict__ ker,
    float* __restrict__ out) {
  __shared__ unsigned short offs[KK * 64];  // 3.375 KB

  const int tid = threadIdx.x;
  const int blk = blockIdx.x;
  const int b   = blk >> 10;
  const int p   = (blk >> 9) & 1;
  const int s0  = (blk & 511) << 6;
  const int si  = tid & 63;
  const int w   = __builtin_amdgcn_readfirstlane(tid >> 6);
  const int g   = (p << 2) + w;
  const int c0  = g << 3;

  // Offset table: f = k*32768 + s, mixed radix
  // [od:32][oh:32][ow:32][kd:3][kh:3][kw:3];
  // (dd,hh,ww) = (od+kd-1, oh+kh-1, ow+kw-1); 0xFFFF if OOB (zero pad).
  for (int i = tid; i < KK * 64; i += 256) {
    int k  = i >> 6;
    int f  = (k << 15) + s0 + (i & 63);
    int kw = f % 3; int u = f / 3;
    int kh = u % 3; u /= 3;
    int kd = u % 3; u /= 3;
    int ww = (u & 31) + kw - 1; u >>= 5;
    int hh = (u & 31) + kh - 1; u >>= 5;
    int dd = u + kd - 1;
    unsigned short off = 0xFFFFu;
    if (((unsigned)ww < 32u) & ((unsigned)hh < 32u) & ((unsigned)dd < 32u))
      off = (unsigned short)((dd << 10) + (hh << 5) + ww);
    offs[i] = off;
  }
  __syncthreads();

  const float* kb  = ker + (((size_t)(b * 216 + g * KK)) << 15) + s0 + si;
  const float* xTb = xT + ((size_t)b << 21) + c0;

  float oacc[8];
#pragma unroll
  for (int i = 0; i < 8; ++i) oacc[i] = 0.f;

#pragma unroll 2
  for (int k = 0; k < KK; ++k) {
    unsigned off = offs[(k << 6) + si];
    float kvr = kb[(size_t)k << 15];
    float kv  = (off != 0xFFFFu) ? kvr : 0.f;
    unsigned o2 = (off != 0xFFFFu) ? off : 0u;
    const float* xp = xTb + ((size_t)o2 << 6);
    float4 v0 = *(const float4*)xp;
    float4 v1 = *(const float4*)(xp + 4);
    oacc[0] = fmaf(kv, v0.x, oacc[0]);
    oacc[1] = fmaf(kv, v0.y, oacc[1]);
    oacc[2] = fmaf(kv, v0.z, oacc[2]);
    oacc[3] = fmaf(kv, v0.w, oacc[3]);
    oacc[4] = fmaf(kv, v1.x, oacc[4]);
    oacc[5] = fmaf(kv, v1.y, oacc[5]);
    oacc[6] = fmaf(kv, v1.z, oacc[6]);
    oacc[7] = fmaf(kv, v1.w, oacc[7]);
  }

  float* ob = out + (((size_t)b * CC + c0) << 15) + s0 + si;
#pragma unroll
  for (int i = 0; i < 8; ++i) ob[(size_t)i << 15] = oacc[i];
}

// ---------------------------------------------------------------------------
// Fallback (ws too small): exact R4 fused kernel — known-good 144 us.
// ---------------------------------------------------------------------------
__global__ __launch_bounds__(256, 8) void invol_fused(
    const float* __restrict__ x, const float* __restrict__ wr,
    const float* __restrict__ wsp, const float* __restrict__ gamma,
    const float* __restrict__ beta, const float* __restrict__ mean,
    const float* __restrict__ var, float* __restrict__ out) {
  __shared__ float sv[CC * 64];
  __shared__ int offs[KK * 64];

  const int tid = threadIdx.x;
  const int blk = blockIdx.x;
  const int b   = blk >> 10;
  const int p   = (blk >> 9) & 1;
  const int s0  = (blk & 511) << 6;
  const int si  = tid & 63;
  const int w   = __builtin_amdgcn_readfirstlane(tid >> 6);
  const int g   = (p << 2) + w;

  const float* xb  = x + ((size_t)b << 21);
  const float* xs0 = xb + s0 + si;

  for (int i = tid; i < KK * 64; i += 256) {
    int k  = i >> 6;
    int f  = (k << 15) + s0 + (i & 63);
    int kw = f % 3; int u = f / 3;
    int kh = u % 3; u /= 3;
    int kd = u % 3; u /= 3;
    int ww = (u & 31) + kw - 1; u >>= 5;
    int hh = (u & 31) + kh - 1; u >>= 5;
    int dd = u + kd - 1;
    int off = -1;
    if (((unsigned)ww < 32u) & ((unsigned)hh < 32u) & ((unsigned)dd < 32u))
      off = (dd << 10) + (hh << 5) + ww;
    offs[i] = off;
  }

  {
    float acc[16];
#pragma unroll
    for (int j = 0; j < 16; ++j) acc[j] = 0.f;
#pragma unroll
    for (int half = 0; half < 2; ++half) {
      float xv[32];
#pragma unroll
      for (int c = 0; c < 32; ++c)
        xv[c] = xs0[(size_t)(half * 32 + c) << 15];
      const float* wrw = wr + (w * 16) * CC + half * 32;
#pragma unroll
      for (int j = 0; j < 16; ++j) {
        const float* r0 = wrw + j * CC;
        float a0 = 0.f, a1 = 0.f;
#pragma unroll
        for (int c = 0; c < 32; c += 2) {
          a0 = fmaf(r0[c],     xv[c],     a0);
          a1 = fmaf(r0[c + 1], xv[c + 1], a1);
        }
        acc[j] += a0 + a1;
      }
    }
#pragma unroll
    for (int j = 0; j < 16; ++j) {
      int o = w * 16 + j;
      float v = (acc[j] - mean[o]) * rsqrtf(var[o] + BN_EPS) * gamma[o] + beta[o];
      sv[o * 64 + si] = v > 0.f ? v : 0.f;
    }
  }
  __syncthreads();

  float kreg[27];
#pragma unroll
  for (int j = 0; j < KK; ++j) kreg[j] = 0.f;
#pragma unroll
  for (int e = 0; e < 8; ++e) {
    float xv[8];
#pragma unroll
    for (int c = 0; c < 8; ++c) xv[c] = sv[(e * 8 + c) * 64 + si];
    const float* wsw = wsp + (g * KK) * CC + e * 8;
#pragma unroll
    for (int j = 0; j < KK; ++j) {
      const float* r = wsw + j * CC;
      float a0 = 0.f, a1 = 0.f;
#pragma unroll
      for (int c = 0; c < 8; c += 2) {
        a0 = fmaf(r[c],     xv[c],     a0);
        a1 = fmaf(r[c + 1], xv[c + 1], a1);
      }
      kreg[j] += a0 + a1;
    }
  }

  {
    const int c0 = g << 3;
    const float* xc0 = xb + ((size_t)c0 << 15);
    float oacc[8];
#pragma unroll
    for (int i = 0; i < 8; ++i) oacc[i] = 0.f;
#pragma unroll
    for (int k = 0; k < KK; ++k) {
      int off = offs[(k << 6) + si];
      float kv = kreg[k];
      if (off >= 0) {
#pragma unroll
        for (int c8 = 0; c8 < 8; ++c8)
          oacc[c8] = fmaf(kv, xc0[off + (c8 << 15)], oacc[c8]);
      }
    }
    float* ob = out + (((size_t)b * CC + c0) << 15) + s0 + si;
#pragma unroll
    for (int i = 0; i < 8; ++i) ob[(size_t)i << 15] = oacc[i];
  }
}

extern "C" void kernel_launch(void* const* d_in, const int* in_sizes, int n_in,
                              void* d_out, int out_size, void* d_ws, size_t ws_size,
                              hipStream_t stream) {
  const float* x     = (const float*)d_in[0];
  const float* wr    = (const float*)d_in[1];
  const float* wsp   = (const float*)d_in[2];
  const float* gamma = (const float*)d_in[3];
  const float* beta  = (const float*)d_in[4];
  const float* mean  = (const float*)d_in[5];
  const float* var   = (const float*)d_in[6];
  float* out = (float*)d_out;

  const size_t need = (XT_FLOATS + (size_t)BB * 216 * S_TOT) * sizeof(float);  // 73.4 MB
  if (ws_size >= need) {
    float* xT  = (float*)d_ws;
    float* ker = (float*)d_ws + XT_FLOATS;
    xpose_kernel<<<BB * (S_TOT / 64), 256, 0, stream>>>(x, xT);
    kergen_kernel<<<BB * 2 * (S_TOT / 64), 256, 0, stream>>>(
        x, wr, wsp, gamma, beta, mean, var, ker);
    gather_kernel<<<BB * 2 * (S_TOT / 64), 256, 0, stream>>>(xT, ker, out);
  } else {
    invol_fused<<<BB * 2 * (S_TOT / 64), 256, 0, stream>>>(
        x, wr, wsp, gamma, beta, mean, var, out);
  }
}

// Round 10
// 150.830 us; speedup vs baseline: 2.0549x; 2.0549x over previous
//
#include <hip/hip_runtime.h>

// Problem constants
#define BB 2
#define CC 64
#define KK 27
#define S_TOT 32768  // 32^3
#define BN_EPS 1e-5f

// ws layout: xT[2][32768][64] floats (16.8 MB) then ker[2][216][32768] (56.6 MB)
#define XT_FLOATS ((size_t)BB * S_TOT * CC)

// ---------------------------------------------------------------------------
// K1: transpose x[b][c][s] -> xT[b][s][c]  (LDS-tiled, verified since R5).
// ---------------------------------------------------------------------------
__global__ __launch_bounds__(256) void xpose_kernel(const float* __restrict__ x,
                                                    float* __restrict__ xT) {
  __shared__ float t[64 * 65];
  const int tid = threadIdx.x;
  const int blk = blockIdx.x;
  const int b   = blk >> 9;
  const int s0  = (blk & 511) << 6;
  const float* xb = x + ((size_t)b << 21);
  {
    const int cq = tid >> 4;
    const int sq = (tid & 15) << 2;
#pragma unroll
    for (int i = 0; i < 4; ++i) {
      int c = cq + (i << 4);
      float4 v = *(const float4*)(xb + ((size_t)c << 15) + s0 + sq);
      t[c * 65 + sq + 0] = v.x;
      t[c * 65 + sq + 1] = v.y;
      t[c * 65 + sq + 2] = v.z;
      t[c * 65 + sq + 3] = v.w;
    }
  }
  __syncthreads();
  {
    float* xTb = xT + ((size_t)b << 21);
    const int si = tid >> 2;
    const int cb = (tid & 3) << 4;
#pragma unroll
    for (int j = 0; j < 4; ++j) {
      int c = cb + (j << 2);
      float4 w;
      w.x = t[(c + 0) * 65 + si];
      w.y = t[(c + 1) * 65 + si];
      w.z = t[(c + 2) * 65 + si];
      w.w = t[(c + 3) * 65 + si];
      *(float4*)(xTb + ((size_t)(s0 + si) << 6) + c) = w;
    }
  }
}

// ---------------------------------------------------------------------------
// K2: kernel generation. Block (b, p, tile), 4 waves; wave w owns group
// g=4p+w. GEMM2's j-dim tiled in 3 chunks of 9 via a RUNTIME loop
// (#pragma unroll 1): the loop backedge is the only thing that actually
// bounds live pressure — R9's compile-time-unrolled chunks were re-fused by
// the scheduler, materializing 27 store-address pairs (128KB strides exceed
// the 13-bit store immediate) and spilling every array. Per-iteration live:
// acc[9] + xv[8] + 9 addr pairs ~= 45 VGPR. All array indices static.
// ---------------------------------------------------------------------------
__global__ __launch_bounds__(256, 6) void kergen_kernel(
    const float* __restrict__ x, const float* __restrict__ wr,
    const float* __restrict__ wsp, const float* __restrict__ gamma,
    const float* __restrict__ beta, const float* __restrict__ mean,
    const float* __restrict__ var, float* __restrict__ ker) {
  __shared__ float sv[CC * 64];  // 16 KB

  const int tid = threadIdx.x;
  const int blk = blockIdx.x;
  const int b   = blk >> 10;
  const int p   = (blk >> 9) & 1;
  const int s0  = (blk & 511) << 6;
  const int si  = tid & 63;
  const int w   = __builtin_amdgcn_readfirstlane(tid >> 6);
  const int g   = (p << 2) + w;

  const float* xs0 = x + ((size_t)b << 21) + s0 + si;

  // GEMM1 + BN + ReLU -> sv (wave w computes channels 16w..16w+15)
  {
    float acc[16];
#pragma unroll
    for (int j = 0; j < 16; ++j) acc[j] = 0.f;
#pragma unroll
    for (int half = 0; half < 2; ++half) {
      float xv[32];
#pragma unroll
      for (int c = 0; c < 32; ++c)
        xv[c] = xs0[(size_t)(half * 32 + c) << 15];
      const float* wrw = wr + (w * 16) * CC + half * 32;
#pragma unroll
      for (int j = 0; j < 16; ++j) {
        const float* r0 = wrw + j * CC;
        float a0 = 0.f, a1 = 0.f;
#pragma unroll
        for (int c = 0; c < 32; c += 2) {
          a0 = fmaf(r0[c],     xv[c],     a0);
          a1 = fmaf(r0[c + 1], xv[c + 1], a1);
        }
        acc[j] += a0 + a1;
      }
    }
#pragma unroll
    for (int j = 0; j < 16; ++j) {
      int o = w * 16 + j;
      float v = (acc[j] - mean[o]) * rsqrtf(var[o] + BN_EPS) * gamma[o] + beta[o];
      sv[o * 64 + si] = v > 0.f ? v : 0.f;
    }
  }
  __syncthreads();

  // GEMM2 -> ker, j tiled by 9, RUNTIME chunk loop (no unroll!)
  float* kb = ker + (((size_t)(b * 216 + g * KK)) << 15) + s0 + si;
#pragma unroll 1
  for (int jt = 0; jt < 3; ++jt) {
    float acc[9];
#pragma unroll
    for (int j = 0; j < 9; ++j) acc[j] = 0.f;
    const float* wsb = wsp + (g * KK + jt * 9) * CC;
#pragma unroll
    for (int e = 0; e < 8; ++e) {
      float xv[8];
#pragma unroll
      for (int c = 0; c < 8; ++c) xv[c] = sv[(e * 8 + c) * 64 + si];
      const float* wsw = wsb + e * 8;
#pragma unroll
      for (int j = 0; j < 9; ++j) {
        const float* r = wsw + j * CC;
        float a0 = 0.f, a1 = 0.f;
#pragma unroll
        for (int c = 0; c < 8; c += 2) {
          a0 = fmaf(r[c],     xv[c],     a0);
          a1 = fmaf(r[c + 1], xv[c + 1], a1);
        }
        acc[j] += a0 + a1;
      }
    }
    float* kbt = kb + ((size_t)(jt * 9) << 15);
#pragma unroll
    for (int j = 0; j < 9; ++j)
      kbt[(size_t)j << 15] = acc[j];
  }
}

// ---------------------------------------------------------------------------
// K3: gather-reduce (unchanged — off the critical path in R8/R9). Rolled
// k-loop, no kreg array; ker + xT are L3-resident.
// ---------------------------------------------------------------------------
__global__ __launch_bounds__(256, 8) void gather_kernel(
    const float* __restrict__ xT, const float* __restrict__ ker,
    float* __restrict__ out) {
  __shared__ unsigned short offs[KK * 64];  // 3.375 KB

  const int tid = threadIdx.x;
  const int blk = blockIdx.x;
  const int b   = blk >> 10;
  const int p   = (blk >> 9) & 1;
  const int s0  = (blk & 511) << 6;
  const int si  = tid & 63;
  const int w   = __builtin_amdgcn_readfirstlane(tid >> 6);
  const int g   = (p << 2) + w;
  const int c0  = g << 3;

  // Offset table: f = k*32768 + s, mixed radix
  // [od:32][oh:32][ow:32][kd:3][kh:3][kw:3];
  // (dd,hh,ww) = (od+kd-1, oh+kh-1, ow+kw-1); 0xFFFF if OOB (zero pad).
  for (int i = tid; i < KK * 64; i += 256) {
    int k  = i >> 6;
    int f  = (k << 15) + s0 + (i & 63);
    int kw = f % 3; int u = f / 3;
    int kh = u % 3; u /= 3;
    int kd = u % 3; u /= 3;
    int ww = (u & 31) + kw - 1; u >>= 5;
    int hh = (u & 31) + kh - 1; u >>= 5;
    int dd = u + kd - 1;
    unsigned short off = 0xFFFFu;
    if (((unsigned)ww < 32u) & ((unsigned)hh < 32u) & ((unsigned)dd < 32u))
      off = (unsigned short)((dd << 10) + (hh << 5) + ww);
    offs[i] = off;
  }
  __syncthreads();

  const float* kb  = ker + (((size_t)(b * 216 + g * KK)) << 15) + s0 + si;
  const float* xTb = xT + ((size_t)b << 21) + c0;

  float oacc[8];
#pragma unroll
  for (int i = 0; i < 8; ++i) oacc[i] = 0.f;

#pragma unroll 2
  for (int k = 0; k < KK; ++k) {
    unsigned off = offs[(k << 6) + si];
    float kvr = kb[(size_t)k << 15];
    float kv  = (off != 0xFFFFu) ? kvr : 0.f;
    unsigned o2 = (off != 0xFFFFu) ? off : 0u;
    const float* xp = xTb + ((size_t)o2 << 6);
    float4 v0 = *(const float4*)xp;
    float4 v1 = *(const float4*)(xp + 4);
    oacc[0] = fmaf(kv, v0.x, oacc[0]);
    oacc[1] = fmaf(kv, v0.y, oacc[1]);
    oacc[2] = fmaf(kv, v0.z, oacc[2]);
    oacc[3] = fmaf(kv, v0.w, oacc[3]);
    oacc[4] = fmaf(kv, v1.x, oacc[4]);
    oacc[5] = fmaf(kv, v1.y, oacc[5]);
    oacc[6] = fmaf(kv, v1.z, oacc[6]);
    oacc[7] = fmaf(kv, v1.w, oacc[7]);
  }

  float* ob = out + (((size_t)b * CC + c0) << 15) + s0 + si;
#pragma unroll
  for (int i = 0; i < 8; ++i) ob[(size_t)i << 15] = oacc[i];
}

// ---------------------------------------------------------------------------
// Fallback (ws too small): exact R4 fused kernel — known-good 144 us.
// ---------------------------------------------------------------------------
__global__ __launch_bounds__(256, 8) void invol_fused(
    const float* __restrict__ x, const float* __restrict__ wr,
    const float* __restrict__ wsp, const float* __restrict__ gamma,
    const float* __restrict__ beta, const float* __restrict__ mean,
    const float* __restrict__ var, float* __restrict__ out) {
  __shared__ float sv[CC * 64];
  __shared__ int offs[KK * 64];

  const int tid = threadIdx.x;
  const int blk = blockIdx.x;
  const int b   = blk >> 10;
  const int p   = (blk >> 9) & 1;
  const int s0  = (blk & 511) << 6;
  const int si  = tid & 63;
  const int w   = __builtin_amdgcn_readfirstlane(tid >> 6);
  const int g   = (p << 2) + w;

  const float* xb  = x + ((size_t)b << 21);
  const float* xs0 = xb + s0 + si;

  for (int i = tid; i < KK * 64; i += 256) {
    int k  = i >> 6;
    int f  = (k << 15) + s0 + (i & 63);
    int kw = f % 3; int u = f / 3;
    int kh = u % 3; u /= 3;
    int kd = u % 3; u /= 3;
    int ww = (u & 31) + kw - 1; u >>= 5;
    int hh = (u & 31) + kh - 1; u >>= 5;
    int dd = u + kd - 1;
    int off = -1;
    if (((unsigned)ww < 32u) & ((unsigned)hh < 32u) & ((unsigned)dd < 32u))
      off = (dd << 10) + (hh << 5) + ww;
    offs[i] = off;
  }

  {
    float acc[16];
#pragma unroll
    for (int j = 0; j < 16; ++j) acc[j] = 0.f;
#pragma unroll
    for (int half = 0; half < 2; ++half) {
      float xv[32];
#pragma unroll
      for (int c = 0; c < 32; ++c)
        xv[c] = xs0[(size_t)(half * 32 + c) << 15];
      const float* wrw = wr + (w * 16) * CC + half * 32;
#pragma unroll
      for (int j = 0; j < 16; ++j) {
        const float* r0 = wrw + j * CC;
        float a0 = 0.f, a1 = 0.f;
#pragma unroll
        for (int c = 0; c < 32; c += 2) {
          a0 = fmaf(r0[c],     xv[c],     a0);
          a1 = fmaf(r0[c + 1], xv[c + 1], a1);
        }
        acc[j] += a0 + a1;
      }
    }
#pragma unroll
    for (int j = 0; j < 16; ++j) {
      int o = w * 16 + j;
      float v = (acc[j] - mean[o]) * rsqrtf(var[o] + BN_EPS) * gamma[o] + beta[o];
      sv[o * 64 + si] = v > 0.f ? v : 0.f;
    }
  }
  __syncthreads();

  float kreg[27];
#pragma unroll
  for (int j = 0; j < KK; ++j) kreg[j] = 0.f;
#pragma unroll
  for (int e = 0; e < 8; ++e) {
    float xv[8];
#pragma unroll
    for (int c = 0; c < 8; ++c) xv[c] = sv[(e * 8 + c) * 64 + si];
    const float* wsw = wsp + (g * KK) * CC + e * 8;
#pragma unroll
    for (int j = 0; j < KK; ++j) {
      const float* r = wsw + j * CC;
      float a0 = 0.f, a1 = 0.f;
#pragma unroll
      for (int c = 0; c < 8; c += 2) {
        a0 = fmaf(r[c],     xv[c],     a0);
        a1 = fmaf(r[c + 1], xv[c + 1], a1);
      }
      kreg[j] += a0 + a1;
    }
  }

  {
    const int c0 = g << 3;
    const float* xc0 = xb + ((size_t)c0 << 15);
    float oacc[8];
#pragma unroll
    for (int i = 0; i < 8; ++i) oacc[i] = 0.f;
#pragma unroll
    for (int k = 0; k < KK; ++k) {
      int off = offs[(k << 6) + si];
      float kv = kreg[k];
      if (off >= 0) {
#pragma unroll
        for (int c8 = 0; c8 < 8; ++c8)
          oacc[c8] = fmaf(kv, xc0[off + (c8 << 15)], oacc[c8]);
      }
    }
    float* ob = out + (((size_t)b * CC + c0) << 15) + s0 + si;
#pragma unroll
    for (int i = 0; i < 8; ++i) ob[(size_t)i << 15] = oacc[i];
  }
}

extern "C" void kernel_launch(void* const* d_in, const int* in_sizes, int n_in,
                              void* d_out, int out_size, void* d_ws, size_t ws_size,
                              hipStream_t stream) {
  const float* x     = (const float*)d_in[0];
  const float* wr    = (const float*)d_in[1];
  const float* wsp   = (const float*)d_in[2];
  const float* gamma = (const float*)d_in[3];
  const float* beta  = (const float*)d_in[4];
  const float* mean  = (const float*)d_in[5];
  const float* var   = (const float*)d_in[6];
  float* out = (float*)d_out;

  const size_t need = (XT_FLOATS + (size_t)BB * 216 * S_TOT) * sizeof(float);  // 73.4 MB
  if (ws_size >= need) {
    float* xT  = (float*)d_ws;
    float* ker = (float*)d_ws + XT_FLOATS;
    xpose_kernel<<<BB * (S_TOT / 64), 256, 0, stream>>>(x, xT);
    kergen_kernel<<<BB * 2 * (S_TOT / 64), 256, 0, stream>>>(
        x, wr, wsp, gamma, beta, mean, var, ker);
    gather_kernel<<<BB * 2 * (S_TOT / 64), 256, 0, stream>>>(xT, ker, out);
  } else {
    invol_fused<<<BB * 2 * (S_TOT / 64), 256, 0, stream>>>(
        x, wr, wsp, gamma, beta, mean, var, out);
  }
}

// Round 11
// 146.758 us; speedup vs baseline: 2.1119x; 1.0277x over previous
//
#include <hip/hip_runtime.h>

// Problem constants
#define BB 2
#define CC 64
#define KK 27
#define S_TOT 32768  // 32^3
#define BN_EPS 1e-5f

// ws layout: xT[2][32768][64] floats (16.8 MB), then
// ker[b][g][tile(512)][k(27)][si(64)] (56.6 MB).
// ker k-stride = 64 floats = 256 B -> per-(g,tile) the 27 rows are one
// contiguous 6.9 KB span: store immediates fit 13 bits, gather re-reads the
// same small span (L2-friendly). Old layout scattered them over 3.4 MB.
#define XT_FLOATS ((size_t)BB * S_TOT * CC)
#define KER_TILE_STRIDE (KK * 64)  // 1728 floats

// ---------------------------------------------------------------------------
// K1: transpose x[b][c][s] -> xT[b][s][c]  (LDS-tiled, verified since R5).
// ---------------------------------------------------------------------------
__global__ __launch_bounds__(256) void xpose_kernel(const float* __restrict__ x,
                                                    float* __restrict__ xT) {
  __shared__ float t[64 * 65];
  const int tid = threadIdx.x;
  const int blk = blockIdx.x;
  const int b   = blk >> 9;
  const int s0  = (blk & 511) << 6;
  const float* xb = x + ((size_t)b << 21);
  {
    const int cq = tid >> 4;
    const int sq = (tid & 15) << 2;
#pragma unroll
    for (int i = 0; i < 4; ++i) {
      int c = cq + (i << 4);
      float4 v = *(const float4*)(xb + ((size_t)c << 15) + s0 + sq);
      t[c * 65 + sq + 0] = v.x;
      t[c * 65 + sq + 1] = v.y;
      t[c * 65 + sq + 2] = v.z;
      t[c * 65 + sq + 3] = v.w;
    }
  }
  __syncthreads();
  {
    float* xTb = xT + ((size_t)b << 21);
    const int si = tid >> 2;
    const int cb = (tid & 3) << 4;
#pragma unroll
    for (int j = 0; j < 4; ++j) {
      int c = cb + (j << 2);
      float4 w;
      w.x = t[(c + 0) * 65 + si];
      w.y = t[(c + 1) * 65 + si];
      w.z = t[(c + 2) * 65 + si];
      w.w = t[(c + 3) * 65 + si];
      *(float4*)(xTb + ((size_t)(s0 + si) << 6) + c) = w;
    }
  }
}

// ---------------------------------------------------------------------------
// K2: kernel generation. Block (b, p, tile), 4 waves; wave w owns group
// g=4p+w. GEMM2 j-dim tiled in 3 chunks of 9 via RUNTIME loop (backedge
// bounds live pressure — R9 lesson). NEW: contiguous ker layout -> 9 stores
// per chunk share one base address with 256B immediates.
// ---------------------------------------------------------------------------
__global__ __launch_bounds__(256, 6) void kergen_kernel(
    const float* __restrict__ x, const float* __restrict__ wr,
    const float* __restrict__ wsp, const float* __restrict__ gamma,
    const float* __restrict__ beta, const float* __restrict__ mean,
    const float* __restrict__ var, float* __restrict__ ker) {
  __shared__ float sv[CC * 64];  // 16 KB

  const int tid  = threadIdx.x;
  const int blk  = blockIdx.x;
  const int b    = blk >> 10;
  const int p    = (blk >> 9) & 1;
  const int tile = blk & 511;
  const int s0   = tile << 6;
  const int si   = tid & 63;
  const int w    = __builtin_amdgcn_readfirstlane(tid >> 6);
  const int g    = (p << 2) + w;

  const float* xs0 = x + ((size_t)b << 21) + s0 + si;

  // GEMM1 + BN + ReLU -> sv (wave w computes channels 16w..16w+15)
  {
    float acc[16];
#pragma unroll
    for (int j = 0; j < 16; ++j) acc[j] = 0.f;
#pragma unroll
    for (int half = 0; half < 2; ++half) {
      float xv[32];
#pragma unroll
      for (int c = 0; c < 32; ++c)
        xv[c] = xs0[(size_t)(half * 32 + c) << 15];
      const float* wrw = wr + (w * 16) * CC + half * 32;
#pragma unroll
      for (int j = 0; j < 16; ++j) {
        const float* r0 = wrw + j * CC;
        float a0 = 0.f, a1 = 0.f;
#pragma unroll
        for (int c = 0; c < 32; c += 2) {
          a0 = fmaf(r0[c],     xv[c],     a0);
          a1 = fmaf(r0[c + 1], xv[c + 1], a1);
        }
        acc[j] += a0 + a1;
      }
    }
#pragma unroll
    for (int j = 0; j < 16; ++j) {
      int o = w * 16 + j;
      float v = (acc[j] - mean[o]) * rsqrtf(var[o] + BN_EPS) * gamma[o] + beta[o];
      sv[o * 64 + si] = v > 0.f ? v : 0.f;
    }
  }
  __syncthreads();

  // GEMM2 -> ker[b][g][tile][k][si], j tiled by 9, RUNTIME chunk loop
  float* kb = ker + ((size_t)((b * 8 + g) * 512 + tile)) * KER_TILE_STRIDE + si;
#pragma unroll 1
  for (int jt = 0; jt < 3; ++jt) {
    float acc[9];
#pragma unroll
    for (int j = 0; j < 9; ++j) acc[j] = 0.f;
    const float* wsb = wsp + (g * KK + jt * 9) * CC;
#pragma unroll
    for (int e = 0; e < 8; ++e) {
      float xv[8];
#pragma unroll
      for (int c = 0; c < 8; ++c) xv[c] = sv[(e * 8 + c) * 64 + si];
      const float* wsw = wsb + e * 8;
#pragma unroll
      for (int j = 0; j < 9; ++j) {
        const float* r = wsw + j * CC;
        float a0 = 0.f, a1 = 0.f;
#pragma unroll
        for (int c = 0; c < 8; c += 2) {
          a0 = fmaf(r[c],     xv[c],     a0);
          a1 = fmaf(r[c + 1], xv[c + 1], a1);
        }
        acc[j] += a0 + a1;
      }
    }
    float* kbt = kb + jt * 9 * 64;
#pragma unroll
    for (int j = 0; j < 9; ++j)
      kbt[j * 64] = acc[j];   // 256B immediates, one base address
  }
}

// ---------------------------------------------------------------------------
// K3: gather-reduce. Rolled k-loop, no kreg array. ker reads now walk one
// contiguous 6.9 KB span per (g,tile); xT reads are two float4s per k.
// ---------------------------------------------------------------------------
__global__ __launch_bounds__(256, 8) void gather_kernel(
    const float* __restrict__ xT, const float* __restrict__ ker,
    float* __restrict__ out) {
  __shared__ unsigned short offs[KK * 64];  // 3.375 KB

  const int tid  = threadIdx.x;
  const int blk  = blockIdx.x;
  const int b    = blk >> 10;
  const int p    = (blk >> 9) & 1;
  const int tile = blk & 511;
  const int s0   = tile << 6;
  const int si   = tid & 63;
  const int w    = __builtin_amdgcn_readfirstlane(tid >> 6);
  const int g    = (p << 2) + w;
  const int c0   = g << 3;

  // Offset table: f = k*32768 + s, mixed radix
  // [od:32][oh:32][ow:32][kd:3][kh:3][kw:3];
  // (dd,hh,ww) = (od+kd-1, oh+kh-1, ow+kw-1); 0xFFFF if OOB (zero pad).
  for (int i = tid; i < KK * 64; i += 256) {
    int k  = i >> 6;
    int f  = (k << 15) + s0 + (i & 63);
    int kw = f % 3; int u = f / 3;
    int kh = u % 3; u /= 3;
    int kd = u % 3; u /= 3;
    int ww = (u & 31) + kw - 1; u >>= 5;
    int hh = (u & 31) + kh - 1; u >>= 5;
    int dd = u + kd - 1;
    unsigned short off = 0xFFFFu;
    if (((unsigned)ww < 32u) & ((unsigned)hh < 32u) & ((unsigned)dd < 32u))
      off = (unsigned short)((dd << 10) + (hh << 5) + ww);
    offs[i] = off;
  }
  __syncthreads();

  const float* kb  = ker + ((size_t)((b * 8 + g) * 512 + tile)) * KER_TILE_STRIDE + si;
  const float* xTb = xT + ((size_t)b << 21) + c0;

  float oacc[8];
#pragma unroll
  for (int i = 0; i < 8; ++i) oacc[i] = 0.f;

#pragma unroll 2
  for (int k = 0; k < KK; ++k) {
    unsigned off = offs[(k << 6) + si];
    float kvr = kb[k * 64];
    float kv  = (off != 0xFFFFu) ? kvr : 0.f;
    unsigned o2 = (off != 0xFFFFu) ? off : 0u;
    const float* xp = xTb + ((size_t)o2 << 6);
    float4 v0 = *(const float4*)xp;
    float4 v1 = *(const float4*)(xp + 4);
    oacc[0] = fmaf(kv, v0.x, oacc[0]);
    oacc[1] = fmaf(kv, v0.y, oacc[1]);
    oacc[2] = fmaf(kv, v0.z, oacc[2]);
    oacc[3] = fmaf(kv, v0.w, oacc[3]);
    oacc[4] = fmaf(kv, v1.x, oacc[4]);
    oacc[5] = fmaf(kv, v1.y, oacc[5]);
    oacc[6] = fmaf(kv, v1.z, oacc[6]);
    oacc[7] = fmaf(kv, v1.w, oacc[7]);
  }

  float* ob = out + (((size_t)b * CC + c0) << 15) + s0 + si;
#pragma unroll
  for (int i = 0; i < 8; ++i) ob[(size_t)i << 15] = oacc[i];
}

// ---------------------------------------------------------------------------
// Fallback (ws too small): exact R4 fused kernel — known-good 144 us.
// ---------------------------------------------------------------------------
__global__ __launch_bounds__(256, 8) void invol_fused(
    const float* __restrict__ x, const float* __restrict__ wr,
    const float* __restrict__ wsp, const float* __restrict__ gamma,
    const float* __restrict__ beta, const float* __restrict__ mean,
    const float* __restrict__ var, float* __restrict__ out) {
  __shared__ float sv[CC * 64];
  __shared__ int offs[KK * 64];

  const int tid = threadIdx.x;
  const int blk = blockIdx.x;
  const int b   = blk >> 10;
  const int p   = (blk >> 9) & 1;
  const int s0  = (blk & 511) << 6;
  const int si  = tid & 63;
  const int w   = __builtin_amdgcn_readfirstlane(tid >> 6);
  const int g   = (p << 2) + w;

  const float* xb  = x + ((size_t)b << 21);
  const float* xs0 = xb + s0 + si;

  for (int i = tid; i < KK * 64; i += 256) {
    int k  = i >> 6;
    int f  = (k << 15) + s0 + (i & 63);
    int kw = f % 3; int u = f / 3;
    int kh = u % 3; u /= 3;
    int kd = u % 3; u /= 3;
    int ww = (u & 31) + kw - 1; u >>= 5;
    int hh = (u & 31) + kh - 1; u >>= 5;
    int dd = u + kd - 1;
    int off = -1;
    if (((unsigned)ww < 32u) & ((unsigned)hh < 32u) & ((unsigned)dd < 32u))
      off = (dd << 10) + (hh << 5) + ww;
    offs[i] = off;
  }

  {
    float acc[16];
#pragma unroll
    for (int j = 0; j < 16; ++j) acc[j] = 0.f;
#pragma unroll
    for (int half = 0; half < 2; ++half) {
      float xv[32];
#pragma unroll
      for (int c = 0; c < 32; ++c)
        xv[c] = xs0[(size_t)(half * 32 + c) << 15];
      const float* wrw = wr + (w * 16) * CC + half * 32;
#pragma unroll
      for (int j = 0; j < 16; ++j) {
        const float* r0 = wrw + j * CC;
        float a0 = 0.f, a1 = 0.f;
#pragma unroll
        for (int c = 0; c < 32; c += 2) {
          a0 = fmaf(r0[c],     xv[c],     a0);
          a1 = fmaf(r0[c + 1], xv[c + 1], a1);
        }
        acc[j] += a0 + a1;
      }
    }
#pragma unroll
    for (int j = 0; j < 16; ++j) {
      int o = w * 16 + j;
      float v = (acc[j] - mean[o]) * rsqrtf(var[o] + BN_EPS) * gamma[o] + beta[o];
      sv[o * 64 + si] = v > 0.f ? v : 0.f;
    }
  }
  __syncthreads();

  float kreg[27];
#pragma unroll
  for (int j = 0; j < KK; ++j) kreg[j] = 0.f;
#pragma unroll
  for (int e = 0; e < 8; ++e) {
    float xv[8];
#pragma unroll
    for (int c = 0; c < 8; ++c) xv[c] = sv[(e * 8 + c) * 64 + si];
    const float* wsw = wsp + (g * KK) * CC + e * 8;
#pragma unroll
    for (int j = 0; j < KK; ++j) {
      const float* r = wsw + j * CC;
      float a0 = 0.f, a1 = 0.f;
#pragma unroll
      for (int c = 0; c < 8; c += 2) {
        a0 = fmaf(r[c],     xv[c],     a0);
        a1 = fmaf(r[c + 1], xv[c + 1], a1);
      }
      kreg[j] += a0 + a1;
    }
  }

  {
    const int c0 = g << 3;
    const float* xc0 = xb + ((size_t)c0 << 15);
    float oacc[8];
#pragma unroll
    for (int i = 0; i < 8; ++i) oacc[i] = 0.f;
#pragma unroll
    for (int k = 0; k < KK; ++k) {
      int off = offs[(k << 6) + si];
      float kv = kreg[k];
      if (off >= 0) {
#pragma unroll
        for (int c8 = 0; c8 < 8; ++c8)
          oacc[c8] = fmaf(kv, xc0[off + (c8 << 15)], oacc[c8]);
      }
    }
    float* ob = out + (((size_t)b * CC + c0) << 15) + s0 + si;
#pragma unroll
    for (int i = 0; i < 8; ++i) ob[(size_t)i << 15] = oacc[i];
  }
}

extern "C" void kernel_launch(void* const* d_in, const int* in_sizes, int n_in,
                              void* d_out, int out_size, void* d_ws, size_t ws_size,
                              hipStream_t stream) {
  const float* x     = (const float*)d_in[0];
  const float* wr    = (const float*)d_in[1];
  const float* wsp   = (const float*)d_in[2];
  const float* gamma = (const float*)d_in[3];
  const float* beta  = (const float*)d_in[4];
  const float* mean  = (const float*)d_in[5];
  const float* var   = (const float*)d_in[6];
  float* out = (float*)d_out;

  const size_t need = (XT_FLOATS + (size_t)BB * 216 * S_TOT) * sizeof(float);  // 73.4 MB
  if (ws_size >= need) {
    float* xT  = (float*)d_ws;
    float* ker = (float*)d_ws + XT_FLOATS;
    xpose_kernel<<<BB * (S_TOT / 64), 256, 0, stream>>>(x, xT);
    kergen_kernel<<<BB * 2 * (S_TOT / 64), 256, 0, stream>>>(
        x, wr, wsp, gamma, beta, mean, var, ker);
    gather_kernel<<<BB * 2 * (S_TOT / 64), 256, 0, stream>>>(xT, ker, out);
  } else {
    invol_fused<<<BB * 2 * (S_TOT / 64), 256, 0, stream>>>(
        x, wr, wsp, gamma, beta, mean, var, out);
  }
}

// Round 12
// 132.579 us; speedup vs baseline: 2.3377x; 1.1069x over previous
//
#include <hip/hip_runtime.h>
#include <hip/hip_fp16.h>

// Problem constants
#define BB 2
#define CC 64
#define KK 27
#define S_TOT 32768  // 32^3
#define BN_EPS 1e-5f

// ws layout: xT[2][32768][64] floats (16.8 MB). ker no longer materialized.
#define XT_FLOATS ((size_t)BB * S_TOT * CC)

// ---------------------------------------------------------------------------
// K1: transpose x[b][c][s] -> xT[b][s][c]  (LDS-tiled, proven since R5).
// ---------------------------------------------------------------------------
__global__ __launch_bounds__(256) void xpose_kernel(const float* __restrict__ x,
                                                    float* __restrict__ xT) {
  __shared__ float t[64 * 65];
  const int tid = threadIdx.x;
  const int blk = blockIdx.x;
  const int b   = blk >> 9;
  const int s0  = (blk & 511) << 6;
  const float* xb = x + ((size_t)b << 21);
  {
    const int cq = tid >> 4;
    const int sq = (tid & 15) << 2;
#pragma unroll
    for (int i = 0; i < 4; ++i) {
      int c = cq + (i << 4);
      float4 v = *(const float4*)(xb + ((size_t)c << 15) + s0 + sq);
      t[c * 65 + sq + 0] = v.x;
      t[c * 65 + sq + 1] = v.y;
      t[c * 65 + sq + 2] = v.z;
      t[c * 65 + sq + 3] = v.w;
    }
  }
  __syncthreads();
  {
    float* xTb = xT + ((size_t)b << 21);
    const int si = tid >> 2;
    const int cb = (tid & 3) << 4;
#pragma unroll
    for (int j = 0; j < 4; ++j) {
      int c = cb + (j << 2);
      float4 w;
      w.x = t[(c + 0) * 65 + si];
      w.y = t[(c + 1) * 65 + si];
      w.z = t[(c + 2) * 65 + si];
      w.w = t[(c + 3) * 65 + si];
      *(float4*)(xTb + ((size_t)(s0 + si) << 6) + c) = w;
    }
  }
}

// ---------------------------------------------------------------------------
// K2: FUSED kergen + gather. Block (b, p, tile), 4 waves; wave w owns group
// g = 4p + w, lane si owns spatial column s0+si.
//   Phase 0: offs table (u16) -> LDS
//   Phase 1: GEMM1 + BN + ReLU -> sv (x read CONTIGUOUSLY from xT:
//            16 float4/thread instead of 64 scalar loads at 128KB stride)
//   Phase 2: GEMM2 -> kl LDS in fp16 (runtime jt chunk loop, R11-proven).
//            kl is a per-thread indexable register file: thread (w,si)
//            writes kl[w][j][si] and is the ONLY reader (phase 3) -> no
//            second barrier. This resolves the R5/R6 conflict: rolled
//            gather loop needs runtime-indexable ker storage; registers
//            spill (R6), HBM round-trips 114MB (R8-11); LDS does neither.
//   Phase 3: gather from xT (rolled k-loop, #pragma unroll 2, R8-11-proven).
// LDS: sv 16KB + kl 13.5KB + offs 3.4KB = 32.9KB -> 4 blocks/CU.
// One barrier total (covers sv + offs; kl is same-thread).
// ---------------------------------------------------------------------------
__global__ __launch_bounds__(256, 4) void invol_fused_xt(
    const float* __restrict__ xT, const float* __restrict__ wr,
    const float* __restrict__ wsp, const float* __restrict__ gamma,
    const float* __restrict__ beta, const float* __restrict__ mean,
    const float* __restrict__ var, float* __restrict__ out) {
  __shared__ float sv[CC * 64];              // 16 KB
  __shared__ __half kl[4 * KK * 64];         // 13.5 KB
  __shared__ unsigned short offs[KK * 64];   // 3.375 KB

  const int tid  = threadIdx.x;
  const int blk  = blockIdx.x;
  const int b    = blk >> 10;
  const int p    = (blk >> 9) & 1;
  const int s0   = (blk & 511) << 6;
  const int si   = tid & 63;
  const int w    = __builtin_amdgcn_readfirstlane(tid >> 6);  // wave 0..3
  const int g    = (p << 2) + w;                               // group
  const int c0   = g << 3;

  // ---- Phase 0: offset table ----
  // f = k*32768 + s, mixed radix [od:32][oh:32][ow:32][kd:3][kh:3][kw:3];
  // (dd,hh,ww) = (od+kd-1, oh+kh-1, ow+kw-1); 0xFFFF if OOB (zero pad).
  for (int i = tid; i < KK * 64; i += 256) {
    int k  = i >> 6;
    int f  = (k << 15) + s0 + (i & 63);
    int kw = f % 3; int u = f / 3;
    int kh = u % 3; u /= 3;
    int kd = u % 3; u /= 3;
    int ww = (u & 31) + kw - 1; u >>= 5;
    int hh = (u & 31) + kh - 1; u >>= 5;
    int dd = u + kd - 1;
    unsigned short off = 0xFFFFu;
    if (((unsigned)ww < 32u) & ((unsigned)hh < 32u) & ((unsigned)dd < 32u))
      off = (unsigned short)((dd << 10) + (hh << 5) + ww);
    offs[i] = off;
  }

  // ---- Phase 1: GEMM1 + BN + ReLU -> sv (x from xT, contiguous) ----
  {
    const float* xrow = xT + ((((size_t)b << 15) + s0 + si) << 6);  // xT[b][s][*]
    float acc[16];
#pragma unroll
    for (int j = 0; j < 16; ++j) acc[j] = 0.f;
#pragma unroll
    for (int half = 0; half < 2; ++half) {
      float xv[32];
#pragma unroll
      for (int q = 0; q < 8; ++q) {
        float4 v = *(const float4*)(xrow + half * 32 + q * 4);
        xv[q * 4 + 0] = v.x;
        xv[q * 4 + 1] = v.y;
        xv[q * 4 + 2] = v.z;
        xv[q * 4 + 3] = v.w;
      }
      const float* wrw = wr + (w * 16) * CC + half * 32;
#pragma unroll
      for (int j = 0; j < 16; ++j) {
        const float* r0 = wrw + j * CC;
        float a0 = 0.f, a1 = 0.f;
#pragma unroll
        for (int c = 0; c < 32; c += 2) {
          a0 = fmaf(r0[c],     xv[c],     a0);
          a1 = fmaf(r0[c + 1], xv[c + 1], a1);
        }
        acc[j] += a0 + a1;
      }
    }
#pragma unroll
    for (int j = 0; j < 16; ++j) {
      int o = w * 16 + j;
      float v = (acc[j] - mean[o]) * rsqrtf(var[o] + BN_EPS) * gamma[o] + beta[o];
      sv[o * 64 + si] = v > 0.f ? v : 0.f;
    }
  }
  __syncthreads();  // covers sv + offs (only barrier in the kernel)

  // ---- Phase 2: GEMM2 -> kl (fp16 LDS), runtime jt chunk loop ----
  {
    __half* klw = kl + (w * KK) * 64 + si;
#pragma unroll 1
    for (int jt = 0; jt < 3; ++jt) {
      float acc[9];
#pragma unroll
      for (int j = 0; j < 9; ++j) acc[j] = 0.f;
      const float* wsb = wsp + (g * KK + jt * 9) * CC;
#pragma unroll
      for (int e = 0; e < 8; ++e) {
        float xv[8];
#pragma unroll
        for (int c = 0; c < 8; ++c) xv[c] = sv[(e * 8 + c) * 64 + si];
        const float* wsw = wsb + e * 8;
#pragma unroll
        for (int j = 0; j < 9; ++j) {
          const float* r = wsw + j * CC;
          float a0 = 0.f, a1 = 0.f;
#pragma unroll
          for (int c = 0; c < 8; c += 2) {
            a0 = fmaf(r[c],     xv[c],     a0);
            a1 = fmaf(r[c + 1], xv[c + 1], a1);
          }
          acc[j] += a0 + a1;
        }
      }
      __half* klt = klw + jt * 9 * 64;
#pragma unroll
      for (int j = 0; j < 9; ++j)
        klt[j * 64] = __float2half(acc[j]);
    }
  }
  // no barrier: kl[w][*][si] written and read by the SAME thread.

  // ---- Phase 3: gather-reduce from xT (rolled k-loop) ----
  {
    const float* xTb = xT + ((size_t)b << 21) + c0;
    const __half* klr = kl + (w * KK) * 64 + si;
    float oacc[8];
#pragma unroll
    for (int i = 0; i < 8; ++i) oacc[i] = 0.f;

#pragma unroll 2
    for (int k = 0; k < KK; ++k) {
      unsigned off = offs[(k << 6) + si];
      float kvr = __half2float(klr[k * 64]);
      float kv  = (off != 0xFFFFu) ? kvr : 0.f;
      unsigned o2 = (off != 0xFFFFu) ? off : 0u;
      const float* xp = xTb + ((size_t)o2 << 6);
      float4 v0 = *(const float4*)xp;
      float4 v1 = *(const float4*)(xp + 4);
      oacc[0] = fmaf(kv, v0.x, oacc[0]);
      oacc[1] = fmaf(kv, v0.y, oacc[1]);
      oacc[2] = fmaf(kv, v0.z, oacc[2]);
      oacc[3] = fmaf(kv, v0.w, oacc[3]);
      oacc[4] = fmaf(kv, v1.x, oacc[4]);
      oacc[5] = fmaf(kv, v1.y, oacc[5]);
      oacc[6] = fmaf(kv, v1.z, oacc[6]);
      oacc[7] = fmaf(kv, v1.w, oacc[7]);
    }

    float* ob = out + (((size_t)b * CC + c0) << 15) + s0 + si;
#pragma unroll
    for (int i = 0; i < 8; ++i) ob[(size_t)i << 15] = oacc[i];
  }
}

// ---------------------------------------------------------------------------
// Fallback (ws too small): exact R4 fused kernel — known-good 144 us.
// ---------------------------------------------------------------------------
__global__ __launch_bounds__(256, 8) void invol_fused(
    const float* __restrict__ x, const float* __restrict__ wr,
    const float* __restrict__ wsp, const float* __restrict__ gamma,
    const float* __restrict__ beta, const float* __restrict__ mean,
    const float* __restrict__ var, float* __restrict__ out) {
  __shared__ float sv[CC * 64];
  __shared__ int offs[KK * 64];

  const int tid = threadIdx.x;
  const int blk = blockIdx.x;
  const int b   = blk >> 10;
  const int p   = (blk >> 9) & 1;
  const int s0  = (blk & 511) << 6;
  const int si  = tid & 63;
  const int w   = __builtin_amdgcn_readfirstlane(tid >> 6);
  const int g   = (p << 2) + w;

  const float* xb  = x + ((size_t)b << 21);
  const float* xs0 = xb + s0 + si;

  for (int i = tid; i < KK * 64; i += 256) {
    int k  = i >> 6;
    int f  = (k << 15) + s0 + (i & 63);
    int kw = f % 3; int u = f / 3;
    int kh = u % 3; u /= 3;
    int kd = u % 3; u /= 3;
    int ww = (u & 31) + kw - 1; u >>= 5;
    int hh = (u & 31) + kh - 1; u >>= 5;
    int dd = u + kd - 1;
    int off = -1;
    if (((unsigned)ww < 32u) & ((unsigned)hh < 32u) & ((unsigned)dd < 32u))
      off = (dd << 10) + (hh << 5) + ww;
    offs[i] = off;
  }

  {
    float acc[16];
#pragma unroll
    for (int j = 0; j < 16; ++j) acc[j] = 0.f;
#pragma unroll
    for (int half = 0; half < 2; ++half) {
      float xv[32];
#pragma unroll
      for (int c = 0; c < 32; ++c)
        xv[c] = xs0[(size_t)(half * 32 + c) << 15];
      const float* wrw = wr + (w * 16) * CC + half * 32;
#pragma unroll
      for (int j = 0; j < 16; ++j) {
        const float* r0 = wrw + j * CC;
        float a0 = 0.f, a1 = 0.f;
#pragma unroll
        for (int c = 0; c < 32; c += 2) {
          a0 = fmaf(r0[c],     xv[c],     a0);
          a1 = fmaf(r0[c + 1], xv[c + 1], a1);
        }
        acc[j] += a0 + a1;
      }
    }
#pragma unroll
    for (int j = 0; j < 16; ++j) {
      int o = w * 16 + j;
      float v = (acc[j] - mean[o]) * rsqrtf(var[o] + BN_EPS) * gamma[o] + beta[o];
      sv[o * 64 + si] = v > 0.f ? v : 0.f;
    }
  }
  __syncthreads();

  float kreg[27];
#pragma unroll
  for (int j = 0; j < KK; ++j) kreg[j] = 0.f;
#pragma unroll
  for (int e = 0; e < 8; ++e) {
    float xv[8];
#pragma unroll
    for (int c = 0; c < 8; ++c) xv[c] = sv[(e * 8 + c) * 64 + si];
    const float* wsw = wsp + (g * KK) * CC + e * 8;
#pragma unroll
    for (int j = 0; j < KK; ++j) {
      const float* r = wsw + j * CC;
      float a0 = 0.f, a1 = 0.f;
#pragma unroll
      for (int c = 0; c < 8; c += 2) {
        a0 = fmaf(r[c],     xv[c],     a0);
        a1 = fmaf(r[c + 1], xv[c + 1], a1);
      }
      kreg[j] += a0 + a1;
    }
  }

  {
    const int c0 = g << 3;
    const float* xc0 = xb + ((size_t)c0 << 15);
    float oacc[8];
#pragma unroll
    for (int i = 0; i < 8; ++i) oacc[i] = 0.f;
#pragma unroll
    for (int k = 0; k < KK; ++k) {
      int off = offs[(k << 6) + si];
      float kv = kreg[k];
      if (off >= 0) {
#pragma unroll
        for (int c8 = 0; c8 < 8; ++c8)
          oacc[c8] = fmaf(kv, xc0[off + (c8 << 15)], oacc[c8]);
      }
    }
    float* ob = out + (((size_t)b * CC + c0) << 15) + s0 + si;
#pragma unroll
    for (int i = 0; i < 8; ++i) ob[(size_t)i << 15] = oacc[i];
  }
}

extern "C" void kernel_launch(void* const* d_in, const int* in_sizes, int n_in,
                              void* d_out, int out_size, void* d_ws, size_t ws_size,
                              hipStream_t stream) {
  const float* x     = (const float*)d_in[0];
  const float* wr    = (const float*)d_in[1];
  const float* wsp   = (const float*)d_in[2];
  const float* gamma = (const float*)d_in[3];
  const float* beta  = (const float*)d_in[4];
  const float* mean  = (const float*)d_in[5];
  const float* var   = (const float*)d_in[6];
  float* out = (float*)d_out;

  const size_t need = XT_FLOATS * sizeof(float);  // 16.8 MB
  if (ws_size >= need) {
    float* xT = (float*)d_ws;
    xpose_kernel<<<BB * (S_TOT / 64), 256, 0, stream>>>(x, xT);
    invol_fused_xt<<<BB * 2 * (S_TOT / 64), 256, 0, stream>>>(
        xT, wr, wsp, gamma, beta, mean, var, out);
  } else {
    invol_fused<<<BB * 2 * (S_TOT / 64), 256, 0, stream>>>(
        x, wr, wsp, gamma, beta, mean, var, out);
  }
}